// Round 1
// baseline (599.511 us; speedup 1.0000x reference)
//
#include <hip/hip_runtime.h>

#define E_EDGES 800000
#define NN 50000
#define OUT_STRIDE 288

typedef __bf16 bf16;
typedef bf16 bf16x8 __attribute__((ext_vector_type(8)));
typedef float floatx4 __attribute__((ext_vector_type(4)));
typedef unsigned short ushort8v __attribute__((ext_vector_type(8)));

__device__ __forceinline__ unsigned short f2bf(float f){
    unsigned u = __float_as_uint(f);
    u += 0x7fffu + ((u >> 16) & 1u);   // round-to-nearest-even
    return (unsigned short)(u >> 16);
}
__device__ __forceinline__ unsigned pk2(float a, float b){
    return (unsigned)f2bf(a) | ((unsigned)f2bf(b) << 16);
}
// monotone float->uint mapping for atomicMax/Min
__device__ __forceinline__ unsigned encf(float f){
    unsigned u = __float_as_uint(f);
    return (u & 0x80000000u) ? ~u : (u | 0x80000000u);
}
__device__ __forceinline__ float decf(unsigned u){
    return __uint_as_float((u & 0x80000000u) ? (u ^ 0x80000000u) : ~u);
}

// out row layout: [x 0..64 | sum/mean 64..128 | max 128..192 | min 192..256 | u 256..288]
__global__ void init_kernel(float* __restrict__ out, int* __restrict__ cnt){
    long i = (long)blockIdx.x * blockDim.x + threadIdx.x;
    if (i < (long)NN * 192) {
        int nd = (int)(i / 192);
        int c  = (int)(i % 192);
        // sum=0.0f (bits 0), max=0u (< enc(-inf)=0x007FFFFF), min=~0u (> enc(+inf))
        unsigned v = (c < 128) ? 0u : 0xFFFFFFFFu;
        ((unsigned*)out)[(long)nd * OUT_STRIDE + 64 + c] = v;
    }
    if (i < NN) cnt[i] = 0;
}

// pack W[k][n] into B-fragment order: frag f=(nt*4+kc)*64+lane, elem j:
//   wp[f*8+j] = bf16(W[kc*32 + (lane>>4)*8 + j][nt*16 + (lane&15)])
__global__ void prepack_kernel(const float* __restrict__ W1, const float* __restrict__ W2,
                               const float* __restrict__ W3, unsigned short* __restrict__ wp){
    int i = blockIdx.x * blockDim.x + threadIdx.x;
    if (i >= 40960) return;
    const float* W; int N; int idx;
    if (i < 16384)      { W = W1; N = 128; idx = i; }
    else if (i < 32768) { W = W2; N = 128; idx = i - 16384; }
    else                { W = W3; N = 64;  idx = i - 32768; }
    int j = idx & 7, lane = (idx >> 3) & 63, kc = (idx >> 9) & 3, nt = idx >> 11;
    int k = kc*32 + (lane >> 4)*8 + j;
    int n = nt*16 + (lane & 15);
    wp[i] = f2bf(W[k*N + n]);
}

__global__ __launch_bounds__(256, 4) void edge_mlp_kernel(
    const float* __restrict__ x, const int* __restrict__ ei,
    const unsigned short* __restrict__ wp,
    const float* __restrict__ b1, const float* __restrict__ b2, const float* __restrict__ b3,
    float* __restrict__ out, int* __restrict__ cnt)
{
    constexpr int LD = 136;   // 128 + 8 pad (breaks power-of-2 bank stride)
    __shared__ unsigned short bufA[64*LD];
    __shared__ unsigned short bufB[64*LD];
    __shared__ int cols[64];

    const int tid  = threadIdx.x;
    const int base = blockIdx.x * 64;

    { // gather: 4 threads per edge, bf16-convert into LDS A[edge][128]
        int e = tid >> 2, part = tid & 3;
        int ge = base + e;
        int rn = ei[ge];
        int cn = ei[E_EDGES + ge];
        if (part == 0) { cols[e] = cn; atomicAdd(&cnt[cn], 1); }
        const float4* xr = (const float4*)(x + (long)rn*64) + part*4;
        const float4* xc = (const float4*)(x + (long)cn*64) + part*4;
        unsigned* d32 = (unsigned*)(bufA + e*LD);
#pragma unroll
        for (int i = 0; i < 4; i++){
            float4 v = xr[i];
            int o = (part*16 + i*4) >> 1;
            d32[o] = pk2(v.x, v.y); d32[o+1] = pk2(v.z, v.w);
        }
#pragma unroll
        for (int i = 0; i < 4; i++){
            float4 v = xc[i];
            int o = (64 + part*16 + i*4) >> 1;
            d32[o] = pk2(v.x, v.y); d32[o+1] = pk2(v.z, v.w);
        }
    }
    __syncthreads();

    const int lane  = tid & 63;
    const int w     = tid >> 6;
    const int quad  = lane >> 4;
    const int ln    = lane & 15;
    const int mbase = w * 16;
    const ushort8v* wpv = (const ushort8v*)wp;

    // ---- layer 1: bufA -> relu -> bufB ----
    {
        ushort8v a[4];
#pragma unroll
        for (int kc = 0; kc < 4; kc++)
            a[kc] = *(const ushort8v*)(bufA + (mbase + ln)*LD + kc*32 + quad*8);
#pragma unroll
        for (int nt = 0; nt < 8; nt++){
            floatx4 acc = {0.f, 0.f, 0.f, 0.f};
#pragma unroll
            for (int kc = 0; kc < 4; kc++){
                ushort8v b = wpv[(nt*4 + kc)*64 + lane];
                acc = __builtin_amdgcn_mfma_f32_16x16x32_bf16(
                    __builtin_bit_cast(bf16x8, a[kc]), __builtin_bit_cast(bf16x8, b), acc, 0, 0, 0);
            }
            int n = nt*16 + ln;
            float bias = b1[n];
            unsigned short* orow = bufB + (mbase + quad*4)*LD + n;
#pragma unroll
            for (int r = 0; r < 4; r++){
                float v = acc[r] + bias;
                v = fmaxf(v, 0.f);
                orow[r*LD] = f2bf(v);
            }
        }
    }
    __syncthreads();

    // ---- layer 2: bufB -> relu -> bufA ----
    {
        ushort8v a[4];
#pragma unroll
        for (int kc = 0; kc < 4; kc++)
            a[kc] = *(const ushort8v*)(bufB + (mbase + ln)*LD + kc*32 + quad*8);
#pragma unroll
        for (int nt = 0; nt < 8; nt++){
            floatx4 acc = {0.f, 0.f, 0.f, 0.f};
#pragma unroll
            for (int kc = 0; kc < 4; kc++){
                ushort8v b = wpv[2048 + (nt*4 + kc)*64 + lane];
                acc = __builtin_amdgcn_mfma_f32_16x16x32_bf16(
                    __builtin_bit_cast(bf16x8, a[kc]), __builtin_bit_cast(bf16x8, b), acc, 0, 0, 0);
            }
            int n = nt*16 + ln;
            float bias = b2[n];
            unsigned short* orow = bufA + (mbase + quad*4)*LD + n;
#pragma unroll
            for (int r = 0; r < 4; r++){
                float v = acc[r] + bias;
                v = fmaxf(v, 0.f);
                orow[r*LD] = f2bf(v);
            }
        }
    }
    __syncthreads();

    // ---- layer 3: bufA -> scatter atomics into out ----
    {
        ushort8v a[4];
#pragma unroll
        for (int kc = 0; kc < 4; kc++)
            a[kc] = *(const ushort8v*)(bufA + (mbase + ln)*LD + kc*32 + quad*8);
#pragma unroll
        for (int nt = 0; nt < 4; nt++){
            floatx4 acc = {0.f, 0.f, 0.f, 0.f};
#pragma unroll
            for (int kc = 0; kc < 4; kc++){
                ushort8v b = wpv[4096 + (nt*4 + kc)*64 + lane];
                acc = __builtin_amdgcn_mfma_f32_16x16x32_bf16(
                    __builtin_bit_cast(bf16x8, a[kc]), __builtin_bit_cast(bf16x8, b), acc, 0, 0, 0);
            }
            int n = nt*16 + ln;
            float bias = b3[n];
#pragma unroll
            for (int r = 0; r < 4; r++){
                int eloc = mbase + quad*4 + r;
                int node = cols[eloc];
                float v = acc[r] + bias;
                float* sp = out + (long)node*OUT_STRIDE + 64;
                atomicAdd(sp + n, v);
                unsigned en = encf(v);
                atomicMax((unsigned*)sp + 64 + n, en);
                atomicMin((unsigned*)sp + 128 + n, en);
            }
        }
    }
}

__global__ void finalize_kernel(const float* __restrict__ x, const float* __restrict__ u,
                                const int* __restrict__ batch, const int* __restrict__ cnt,
                                float* __restrict__ out)
{
    long i = (long)blockIdx.x * blockDim.x + threadIdx.x;
    if (i >= (long)NN * OUT_STRIDE) return;
    int nd = (int)(i / OUT_STRIDE);
    int c  = (int)(i % OUT_STRIDE);
    float v;
    if (c < 64)       v = x[(long)nd*64 + c];
    else if (c < 128) { int k = cnt[nd]; v = out[i] / (float)(k > 0 ? k : 1); }
    else if (c < 256) v = (cnt[nd] > 0) ? decf(((const unsigned*)out)[i]) : 0.f;
    else              v = u[(long)batch[nd]*32 + (c - 256)];
    out[i] = v;
}

extern "C" void kernel_launch(void* const* d_in, const int* in_sizes, int n_in,
                              void* d_out, int out_size, void* d_ws, size_t ws_size,
                              hipStream_t stream)
{
    const float* x     = (const float*)d_in[0];
    const int*   ei    = (const int*)d_in[1];
    // d_in[2] = edge_attr (unused by NodeModel)
    const float* u     = (const float*)d_in[3];
    const int*   batch = (const int*)d_in[4];
    const float* W1    = (const float*)d_in[5];
    const float* b1    = (const float*)d_in[6];
    const float* W2    = (const float*)d_in[7];
    const float* b2    = (const float*)d_in[8];
    const float* W3    = (const float*)d_in[9];
    const float* b3    = (const float*)d_in[10];
    float* out = (float*)d_out;

    unsigned short* wp  = (unsigned short*)d_ws;             // 81920 B packed bf16 weights
    int*            cnt = (int*)((char*)d_ws + 81920);       // 50000 ints

    long initN = (long)NN * 192;
    init_kernel<<<(int)((initN + 255) / 256), 256, 0, stream>>>(out, cnt);
    prepack_kernel<<<160, 256, 0, stream>>>(W1, W2, W3, wp);
    edge_mlp_kernel<<<E_EDGES / 64, 256, 0, stream>>>(x, ei, wp, b1, b2, b3, out, cnt);
    long finN = (long)NN * OUT_STRIDE;
    finalize_kernel<<<(int)((finN + 255) / 256), 256, 0, stream>>>(x, u, batch, cnt, out);
}

// Round 2
// 493.123 us; speedup vs baseline: 1.2157x; 1.2157x over previous
//
#include <hip/hip_runtime.h>

#define E_EDGES 800000
#define NN 50000
#define OUT_STRIDE 288

typedef __bf16 bf16;
typedef bf16 bf16x8 __attribute__((ext_vector_type(8)));
typedef float floatx4 __attribute__((ext_vector_type(4)));
typedef unsigned short ushort8v __attribute__((ext_vector_type(8)));

__device__ __forceinline__ unsigned short f2bf(float f){
    unsigned u = __float_as_uint(f);
    u += 0x7fffu + ((u >> 16) & 1u);   // round-to-nearest-even
    return (unsigned short)(u >> 16);
}
__device__ __forceinline__ unsigned pk2(float a, float b){
    return (unsigned)f2bf(a) | ((unsigned)f2bf(b) << 16);
}
__device__ __forceinline__ float bf2f(unsigned short us){
    return __uint_as_float(((unsigned)us) << 16);
}
// monotone float->uint mapping for atomicMax/Min
__device__ __forceinline__ unsigned encf(float f){
    unsigned u = __float_as_uint(f);
    return (u & 0x80000000u) ? ~u : (u | 0x80000000u);
}
__device__ __forceinline__ float decf(unsigned u){
    return __uint_as_float((u & 0x80000000u) ? (u ^ 0x80000000u) : ~u);
}

// ---- counting sort of edges by destination node ----
__global__ void hist_kernel(const int* __restrict__ ei, int* __restrict__ cnt){
    int e = blockIdx.x * blockDim.x + threadIdx.x;
    if (e < E_EDGES) atomicAdd(&cnt[ei[E_EDGES + e]], 1);
}

__global__ void scan_kernel(const int* __restrict__ cnt, int* __restrict__ off_work){
    __shared__ int psum[256];
    int t = threadIdx.x;
    const int CH = (NN + 255) / 256;  // 196
    int beg = t * CH, end = min(beg + CH, NN);
    int s = 0;
    for (int i = beg; i < end; i++) s += cnt[i];
    psum[t] = s;
    __syncthreads();
    for (int d = 1; d < 256; d <<= 1){
        int v = (t >= d) ? psum[t - d] : 0;
        __syncthreads();
        psum[t] += v;
        __syncthreads();
    }
    int run = psum[t] - s;  // exclusive
    for (int i = beg; i < end; i++){ off_work[i] = run; run += cnt[i]; }
}

__global__ void scatter_kernel(const int* __restrict__ ei, int* __restrict__ off_work,
                               int* __restrict__ perm){
    int e = blockIdx.x * blockDim.x + threadIdx.x;
    if (e >= E_EDGES) return;
    int c = ei[E_EDGES + e];
    int pos = atomicAdd(&off_work[c], 1);
    perm[pos] = e;
}

// out row layout: [x 0..64 | sum/mean 64..128 | max 128..192 | min 192..256 | u 256..288]
__global__ void init_kernel(float* __restrict__ out){
    long i = (long)blockIdx.x * blockDim.x + threadIdx.x;
    if (i >= (long)NN * 192) return;
    int nd = (int)(i / 192);
    int c  = (int)(i % 192);
    // sum=0.0f, max=0u (< enc of any float), min=~0u (> enc of any float)
    unsigned v = (c < 64) ? 0u : 0xFFFFFFFFu;
    v = (c < 64) ? 0u : ((c < 128) ? 0u : 0xFFFFFFFFu);
    ((unsigned*)out)[(long)nd * OUT_STRIDE + 64 + c] = v;
}

// pack W[k][n] into B-fragment order: frag f=(nt*4+kc)*64+lane, elem j:
//   wp[f*8+j] = bf16(W[kc*32 + (lane>>4)*8 + j][nt*16 + (lane&15)])
__global__ void prepack_kernel(const float* __restrict__ W1, const float* __restrict__ W2,
                               const float* __restrict__ W3, unsigned short* __restrict__ wp){
    int i = blockIdx.x * blockDim.x + threadIdx.x;
    if (i >= 40960) return;
    const float* W; int N; int idx;
    if (i < 16384)      { W = W1; N = 128; idx = i; }
    else if (i < 32768) { W = W2; N = 128; idx = i - 16384; }
    else                { W = W3; N = 64;  idx = i - 32768; }
    int j = idx & 7, lane = (idx >> 3) & 63, kc = (idx >> 9) & 3, nt = idx >> 11;
    int k = kc * 32 + (lane >> 4) * 8 + j;
    int n = nt * 16 + (lane & 15);
    wp[i] = f2bf(W[k * N + n]);
}

__global__ __launch_bounds__(256, 4) void edge_mlp_kernel(
    const float* __restrict__ x, const int* __restrict__ ei,
    const int* __restrict__ perm, const unsigned short* __restrict__ wp,
    const float* __restrict__ b1, const float* __restrict__ b2, const float* __restrict__ b3,
    float* __restrict__ out)
{
    constexpr int LD  = 136;  // 128 + 8 pad
    constexpr int LD3 = 72;   // layer-3 output row stride (bank-conflict-free write)
    __shared__ unsigned short bufA[64 * LD];
    __shared__ unsigned short bufB[64 * LD];
    __shared__ int cols[64];

    const int tid  = threadIdx.x;
    const int base = blockIdx.x * 64;

    { // gather (sorted edge order): 4 threads per edge, bf16-convert into LDS A[edge][128]
        int e = tid >> 2, part = tid & 3;
        int ge = perm[base + e];
        int rn = ei[ge];
        int cn = ei[E_EDGES + ge];
        if (part == 0) cols[e] = cn;
        const float4* xr = (const float4*)(x + (long)rn * 64) + part * 4;
        const float4* xc = (const float4*)(x + (long)cn * 64) + part * 4;
        unsigned* d32 = (unsigned*)(bufA + e * LD);
#pragma unroll
        for (int i = 0; i < 4; i++){
            float4 v = xr[i];
            int o = (part * 16 + i * 4) >> 1;
            d32[o] = pk2(v.x, v.y); d32[o + 1] = pk2(v.z, v.w);
        }
#pragma unroll
        for (int i = 0; i < 4; i++){
            float4 v = xc[i];
            int o = (64 + part * 16 + i * 4) >> 1;
            d32[o] = pk2(v.x, v.y); d32[o + 1] = pk2(v.z, v.w);
        }
    }
    __syncthreads();

    const int lane  = tid & 63;
    const int w     = tid >> 6;
    const int quad  = lane >> 4;
    const int ln    = lane & 15;
    const int mbase = w * 16;
    const ushort8v* wpv = (const ushort8v*)wp;

    // ---- layer 1: bufA -> relu -> bufB ----
    {
        ushort8v a[4];
#pragma unroll
        for (int kc = 0; kc < 4; kc++)
            a[kc] = *(const ushort8v*)(bufA + (mbase + ln) * LD + kc * 32 + quad * 8);
#pragma unroll
        for (int nt = 0; nt < 8; nt++){
            floatx4 acc = {0.f, 0.f, 0.f, 0.f};
#pragma unroll
            for (int kc = 0; kc < 4; kc++){
                ushort8v b = wpv[(nt * 4 + kc) * 64 + lane];
                acc = __builtin_amdgcn_mfma_f32_16x16x32_bf16(
                    __builtin_bit_cast(bf16x8, a[kc]), __builtin_bit_cast(bf16x8, b), acc, 0, 0, 0);
            }
            int n = nt * 16 + ln;
            float bias = b1[n];
            unsigned short* orow = bufB + (mbase + quad * 4) * LD + n;
#pragma unroll
            for (int r = 0; r < 4; r++){
                float v = acc[r] + bias;
                v = fmaxf(v, 0.f);
                orow[r * LD] = f2bf(v);
            }
        }
    }
    __syncthreads();

    // ---- layer 2: bufB -> relu -> bufA ----
    {
        ushort8v a[4];
#pragma unroll
        for (int kc = 0; kc < 4; kc++)
            a[kc] = *(const ushort8v*)(bufB + (mbase + ln) * LD + kc * 32 + quad * 8);
#pragma unroll
        for (int nt = 0; nt < 8; nt++){
            floatx4 acc = {0.f, 0.f, 0.f, 0.f};
#pragma unroll
            for (int kc = 0; kc < 4; kc++){
                ushort8v b = wpv[2048 + (nt * 4 + kc) * 64 + lane];
                acc = __builtin_amdgcn_mfma_f32_16x16x32_bf16(
                    __builtin_bit_cast(bf16x8, a[kc]), __builtin_bit_cast(bf16x8, b), acc, 0, 0, 0);
            }
            int n = nt * 16 + ln;
            float bias = b2[n];
            unsigned short* orow = bufA + (mbase + quad * 4) * LD + n;
#pragma unroll
            for (int r = 0; r < 4; r++){
                float v = acc[r] + bias;
                v = fmaxf(v, 0.f);
                orow[r * LD] = f2bf(v);
            }
        }
    }
    __syncthreads();

    // ---- layer 3: bufA -> bufB rows (stride LD3), bf16 ----
    {
        ushort8v a[4];
#pragma unroll
        for (int kc = 0; kc < 4; kc++)
            a[kc] = *(const ushort8v*)(bufA + (mbase + ln) * LD + kc * 32 + quad * 8);
#pragma unroll
        for (int nt = 0; nt < 4; nt++){
            floatx4 acc = {0.f, 0.f, 0.f, 0.f};
#pragma unroll
            for (int kc = 0; kc < 4; kc++){
                ushort8v b = wpv[4096 + (nt * 4 + kc) * 64 + lane];
                acc = __builtin_amdgcn_mfma_f32_16x16x32_bf16(
                    __builtin_bit_cast(bf16x8, a[kc]), __builtin_bit_cast(bf16x8, b), acc, 0, 0, 0);
            }
            int n = nt * 16 + ln;
            float bias = b3[n];
            unsigned short* orow = bufB + (mbase + quad * 4) * LD3 + n;
#pragma unroll
            for (int r = 0; r < 4; r++)
                orow[r * LD3] = f2bf(acc[r] + bias);
        }
    }
    __syncthreads();

    // ---- segmented run-reduction over 16 sorted edges per wave, flush per run ----
    {
        int eloc = w * 16;
        int cur  = cols[eloc];
        float v  = bf2f(bufB[eloc * LD3 + lane]);
        float sum = v, mx = v, mn = v;
#pragma unroll
        for (int j = 1; j < 16; j++){
            eloc++;
            int   c  = cols[eloc];
            float vj = bf2f(bufB[eloc * LD3 + lane]);
            if (c != cur){
                float* sp = out + (long)cur * OUT_STRIDE + 64;
                atomicAdd(sp + lane, sum);
                atomicMax((unsigned*)sp + 64 + lane, encf(mx));
                atomicMin((unsigned*)sp + 128 + lane, encf(mn));
                cur = c; sum = vj; mx = vj; mn = vj;
            } else {
                sum += vj; mx = fmaxf(mx, vj); mn = fminf(mn, vj);
            }
        }
        float* sp = out + (long)cur * OUT_STRIDE + 64;
        atomicAdd(sp + lane, sum);
        atomicMax((unsigned*)sp + 64 + lane, encf(mx));
        atomicMin((unsigned*)sp + 128 + lane, encf(mn));
    }
}

__global__ void finalize_kernel(const float* __restrict__ x, const float* __restrict__ u,
                                const int* __restrict__ batch, const int* __restrict__ cnt,
                                float* __restrict__ out)
{
    long i = (long)blockIdx.x * blockDim.x + threadIdx.x;
    if (i >= (long)NN * OUT_STRIDE) return;
    int nd = (int)(i / OUT_STRIDE);
    int c  = (int)(i % OUT_STRIDE);
    float v;
    if (c < 64)       v = x[(long)nd * 64 + c];
    else if (c < 128) { int k = cnt[nd]; v = out[i] / (float)(k > 0 ? k : 1); }
    else if (c < 256) v = (cnt[nd] > 0) ? decf(((const unsigned*)out)[i]) : 0.f;
    else              v = u[(long)batch[nd] * 32 + (c - 256)];
    out[i] = v;
}

extern "C" void kernel_launch(void* const* d_in, const int* in_sizes, int n_in,
                              void* d_out, int out_size, void* d_ws, size_t ws_size,
                              hipStream_t stream)
{
    const float* x     = (const float*)d_in[0];
    const int*   ei    = (const int*)d_in[1];
    // d_in[2] = edge_attr (unused)
    const float* u     = (const float*)d_in[3];
    const int*   batch = (const int*)d_in[4];
    const float* W1    = (const float*)d_in[5];
    const float* b1    = (const float*)d_in[6];
    const float* W2    = (const float*)d_in[7];
    const float* b2    = (const float*)d_in[8];
    const float* W3    = (const float*)d_in[9];
    const float* b3    = (const float*)d_in[10];
    float* out = (float*)d_out;

    // ws layout
    unsigned short* wp       = (unsigned short*)d_ws;                  // 81,920 B
    int*            cnt      = (int*)((char*)d_ws + 81920);            // 200,000 B
    int*            off_work = (int*)((char*)d_ws + 281920);           // 200,000 B
    int*            perm     = (int*)((char*)d_ws + 481920);           // 3,200,000 B

    hipMemsetAsync(cnt, 0, NN * sizeof(int), stream);
    hist_kernel<<<(E_EDGES + 255) / 256, 256, 0, stream>>>(ei, cnt);
    scan_kernel<<<1, 256, 0, stream>>>(cnt, off_work);
    scatter_kernel<<<(E_EDGES + 255) / 256, 256, 0, stream>>>(ei, off_work, perm);

    long initN = (long)NN * 192;
    init_kernel<<<(int)((initN + 255) / 256), 256, 0, stream>>>(out);
    prepack_kernel<<<160, 256, 0, stream>>>(W1, W2, W3, wp);

    edge_mlp_kernel<<<E_EDGES / 64, 256, 0, stream>>>(x, ei, perm, wp, b1, b2, b3, out);

    long finN = (long)NN * OUT_STRIDE;
    finalize_kernel<<<(int)((finN + 255) / 256), 256, 0, stream>>>(x, u, batch, cnt, out);
}

// Round 4
// 437.354 us; speedup vs baseline: 1.3708x; 1.1275x over previous
//
#include <hip/hip_runtime.h>

#define E_EDGES 800000
#define NN 50000
#define OUT_STRIDE 288

typedef __bf16 bf16;
typedef bf16 bf16x8 __attribute__((ext_vector_type(8)));
typedef float floatx4 __attribute__((ext_vector_type(4)));
typedef unsigned short ushort8v __attribute__((ext_vector_type(8)));

__device__ __forceinline__ unsigned short f2bf(float f){
    unsigned u = __float_as_uint(f);
    u += 0x7fffu + ((u >> 16) & 1u);   // round-to-nearest-even
    return (unsigned short)(u >> 16);
}
__device__ __forceinline__ float bf2f(unsigned short us){
    return __uint_as_float(((unsigned)us) << 16);
}
// monotone float<->uint mapping for atomicMax/Min
__device__ __forceinline__ unsigned encf(float f){
    unsigned u = __float_as_uint(f);
    return (u & 0x80000000u) ? ~u : (u | 0x80000000u);
}
__device__ __forceinline__ float decf(unsigned u){
    return __uint_as_float((u & 0x80000000u) ? (u ^ 0x80000000u) : ~u);
}

// ---------------- setup: zero cnt | init out accum | x->bf16 | prepack weights ----------------
#define ZC_N   12500     // cnt zeroing, int4 units (50000 ints)
#define INIT_N 2400000   // out accum init, uint4 units (50000 rows x 48)  [R3 bug: was 600000]
#define XBF_N  800000    // x -> bf16, 4 elems per thread
#define PK_N   40960
#define SETUP_TOTAL (ZC_N + INIT_N + XBF_N + PK_N)

__global__ void setup_kernel(const float* __restrict__ x,
                             const float* __restrict__ W1, const float* __restrict__ W2,
                             const float* __restrict__ W3,
                             unsigned short* __restrict__ wp, unsigned short* __restrict__ xbf,
                             int* __restrict__ cnt, float* __restrict__ out)
{
    int i = blockIdx.x * blockDim.x + threadIdx.x;
    if (i < ZC_N) {
        ((int4*)cnt)[i] = make_int4(0, 0, 0, 0);
        return;
    }
    i -= ZC_N;
    if (i < INIT_N) {
        // out row layout (uint4 units per row of 72):
        //   [x 0..16 | sum 16..32 | max 32..48 | min 48..64 | u 64..72]
        // this inits q in [0,48) mapped at +16: sum(q<16)=0.0f, max-enc(16<=q<32)=0u, min-enc(q>=32)=~0u
        int row = i / 48, q = i % 48;
        uint4 val = (q < 32) ? make_uint4(0u, 0u, 0u, 0u)
                             : make_uint4(0xFFFFFFFFu, 0xFFFFFFFFu, 0xFFFFFFFFu, 0xFFFFFFFFu);
        ((uint4*)out)[(long)row * 72 + 16 + q] = val;
        return;
    }
    i -= INIT_N;
    if (i < XBF_N) {
        float4 v = ((const float4*)x)[i];
        ushort4 o; o.x = f2bf(v.x); o.y = f2bf(v.y); o.z = f2bf(v.z); o.w = f2bf(v.w);
        ((ushort4*)xbf)[i] = o;
        return;
    }
    i -= XBF_N;
    if (i < PK_N) {
        // pack W[k][n] into B-fragment order: frag f=(nt*4+kc)*64+lane, elem j:
        //   wp[f*8+j] = bf16(W[kc*32 + (lane>>4)*8 + j][nt*16 + (lane&15)])
        const float* W; int N; int idx;
        if (i < 16384)      { W = W1; N = 128; idx = i; }
        else if (i < 32768) { W = W2; N = 128; idx = i - 16384; }
        else                { W = W3; N = 64;  idx = i - 32768; }
        int j = idx & 7, lane = (idx >> 3) & 63, kc = (idx >> 9) & 3, nt = idx >> 11;
        int k = kc * 32 + (lane >> 4) * 8 + j;
        int n = nt * 16 + (lane & 15);
        wp[i] = f2bf(W[k * N + n]);
    }
}

// ---------------- counting sort of edges by destination ----------------
__global__ void hist_kernel(const int* __restrict__ ei, int* __restrict__ cnt){
    int e = blockIdx.x * blockDim.x + threadIdx.x;
    if (e < E_EDGES) atomicAdd(&cnt[ei[E_EDGES + e]], 1);
}

__global__ void scan_kernel(const int* __restrict__ cnt, int* __restrict__ off){
    __shared__ int psum[1024];
    int t = threadIdx.x;
    const int CH = 49;  // 1024*49 >= 50000
    int beg = t * CH, end = min(beg + CH, NN);
    int s = 0;
    for (int k = beg; k < end; k++) s += cnt[k];
    psum[t] = s;
    __syncthreads();
    for (int d = 1; d < 1024; d <<= 1){
        int v = (t >= d) ? psum[t - d] : 0;
        __syncthreads();
        psum[t] += v;
        __syncthreads();
    }
    int run = psum[t] - s;  // exclusive prefix
    for (int k = beg; k < end; k++){ off[k] = run; run += cnt[k]; }
}

__global__ void scatter_kernel(const int* __restrict__ ei, int* __restrict__ off,
                               int2* __restrict__ enodes){
    int e = blockIdx.x * blockDim.x + threadIdx.x;
    if (e >= E_EDGES) return;
    int c = ei[E_EDGES + e];
    int r = ei[e];
    int pos = atomicAdd(&off[c], 1);
    enodes[pos] = make_int2(r, c);
}

// ---------------- edge MLP: barrier-free, wave-independent ----------------
__global__ __launch_bounds__(256, 4) void edge_mlp_kernel(
    const unsigned short* __restrict__ xbf, const int2* __restrict__ enodes,
    const unsigned short* __restrict__ wp,
    const float* __restrict__ b1, const float* __restrict__ b2, const float* __restrict__ b3,
    float* __restrict__ out)
{
    constexpr int LD = 136;  // row stride (ushorts), 272B rows (16B aligned)
    __shared__ unsigned short buf[4][16 * LD];

    const int tid  = threadIdx.x;
    const int lane = tid & 63;
    const int w    = tid >> 6;
    const int quad = lane >> 4;
    const int ln   = lane & 15;
    unsigned short* wbuf = buf[w];
    const int ebase = blockIdx.x * 64 + w * 16;

    // edge descriptor: lane ln -> edge ebase+ln (quads duplicate, L1 broadcast)
    int2 nd = enodes[ebase + ln];
    const int cn = nd.y;

    // gather A-fragments straight from global bf16 x rows (exact MFMA A layout)
    const ushort8v* xr = (const ushort8v*)(xbf + (long)nd.x * 64);
    const ushort8v* xc = (const ushort8v*)(xbf + (long)nd.y * 64);
    ushort8v g0 = xr[quad], g1 = xr[4 + quad], g2 = xc[quad], g3 = xc[4 + quad];

    const ushort8v* wpv = (const ushort8v*)wp;

    // ---- layer 1: regs -> relu -> wbuf rows ----
    {
        ushort8v a[4] = {g0, g1, g2, g3};
#pragma unroll
        for (int nt = 0; nt < 8; nt++){
            floatx4 acc = {0.f, 0.f, 0.f, 0.f};
#pragma unroll
            for (int kc = 0; kc < 4; kc++){
                ushort8v b = wpv[(nt * 4 + kc) * 64 + lane];
                acc = __builtin_amdgcn_mfma_f32_16x16x32_bf16(
                    __builtin_bit_cast(bf16x8, a[kc]), __builtin_bit_cast(bf16x8, b), acc, 0, 0, 0);
            }
            int n = nt * 16 + ln;
            float bias = b1[n];
            unsigned short* orow = wbuf + (quad * 4) * LD + n;
#pragma unroll
            for (int r = 0; r < 4; r++)
                orow[r * LD] = f2bf(fmaxf(acc[r] + bias, 0.f));
        }
    }

    // ---- layer 2: wbuf -> relu -> wbuf (wave-internal, data-dep ordered) ----
    {
        ushort8v a[4];
#pragma unroll
        for (int kc = 0; kc < 4; kc++)
            a[kc] = *(const ushort8v*)(wbuf + ln * LD + kc * 32 + quad * 8);
#pragma unroll
        for (int nt = 0; nt < 8; nt++){
            floatx4 acc = {0.f, 0.f, 0.f, 0.f};
#pragma unroll
            for (int kc = 0; kc < 4; kc++){
                ushort8v b = wpv[2048 + (nt * 4 + kc) * 64 + lane];
                acc = __builtin_amdgcn_mfma_f32_16x16x32_bf16(
                    __builtin_bit_cast(bf16x8, a[kc]), __builtin_bit_cast(bf16x8, b), acc, 0, 0, 0);
            }
            int n = nt * 16 + ln;
            float bias = b2[n];
            unsigned short* orow = wbuf + (quad * 4) * LD + n;
#pragma unroll
            for (int r = 0; r < 4; r++)
                orow[r * LD] = f2bf(fmaxf(acc[r] + bias, 0.f));
        }
    }

    // ---- layer 3: wbuf -> column-major packed (ch*16 + edge) ----
    {
        ushort8v a[4];
#pragma unroll
        for (int kc = 0; kc < 4; kc++)
            a[kc] = *(const ushort8v*)(wbuf + ln * LD + kc * 32 + quad * 8);
#pragma unroll
        for (int nt = 0; nt < 4; nt++){
            floatx4 acc = {0.f, 0.f, 0.f, 0.f};
#pragma unroll
            for (int kc = 0; kc < 4; kc++){
                ushort8v b = wpv[4096 + (nt * 4 + kc) * 64 + lane];
                acc = __builtin_amdgcn_mfma_f32_16x16x32_bf16(
                    __builtin_bit_cast(bf16x8, a[kc]), __builtin_bit_cast(bf16x8, b), acc, 0, 0, 0);
            }
            int n = nt * 16 + ln;
            float bias = b3[n];
            ushort4 pk;
            pk.x = f2bf(acc[0] + bias); pk.y = f2bf(acc[1] + bias);
            pk.z = f2bf(acc[2] + bias); pk.w = f2bf(acc[3] + bias);
            *(ushort4*)(wbuf + n * 16 + quad * 4) = pk;  // [ch][edge] layout
        }
    }

    // ---- epilogue: lane = channel, run-reduce over 16 sorted edges (scalar runs) ----
    {
        ushort8v c0 = *(const ushort8v*)(wbuf + lane * 16);
        ushort8v c1 = *(const ushort8v*)(wbuf + lane * 16 + 8);
        float v[16];
#pragma unroll
        for (int j = 0; j < 8; j++){ v[j] = bf2f(c0[j]); v[8 + j] = bf2f(c1[j]); }

        int cur = __builtin_amdgcn_readlane(cn, 0);
        float sum = v[0], mx = v[0], mn = v[0];
#pragma unroll
        for (int j = 1; j < 16; j++){
            int nj = __builtin_amdgcn_readlane(cn, j);
            if (nj != cur){
                float* sp = out + (long)cur * OUT_STRIDE + 64;
                atomicAdd(sp + lane, sum);
                atomicMax((unsigned*)sp + 64 + lane, encf(mx));
                atomicMin((unsigned*)sp + 128 + lane, encf(mn));
                cur = nj; sum = v[j]; mx = v[j]; mn = v[j];
            } else {
                sum += v[j]; mx = fmaxf(mx, v[j]); mn = fminf(mn, v[j]);
            }
        }
        float* sp = out + (long)cur * OUT_STRIDE + 64;
        atomicAdd(sp + lane, sum);
        atomicMax((unsigned*)sp + 64 + lane, encf(mx));
        atomicMin((unsigned*)sp + 128 + lane, encf(mn));
    }
}

// ---------------- finalize: vectorized float4 ----------------
__global__ void finalize_kernel(const float* __restrict__ x, const float* __restrict__ u,
                                const int* __restrict__ batch, const int* __restrict__ cnt,
                                float* __restrict__ out)
{
    long i = (long)blockIdx.x * blockDim.x + threadIdx.x;
    if (i >= (long)NN * 72) return;
    int ndx = (int)(i / 72);
    int q   = (int)(i % 72);
    float4 res;
    if (q < 16) {
        res = ((const float4*)(x + (long)ndx * 64))[q];
    } else if (q < 32) {
        float4 s = ((const float4*)out)[i];
        int k = cnt[ndx];
        float inv = 1.f / (float)(k > 0 ? k : 1);
        res.x = s.x * inv; res.y = s.y * inv; res.z = s.z * inv; res.w = s.w * inv;
    } else if (q < 64) {
        uint4 e = ((const uint4*)out)[i];
        bool ne = cnt[ndx] > 0;
        res.x = ne ? decf(e.x) : 0.f; res.y = ne ? decf(e.y) : 0.f;
        res.z = ne ? decf(e.z) : 0.f; res.w = ne ? decf(e.w) : 0.f;
    } else {
        res = ((const float4*)(u + (long)batch[ndx] * 32))[q - 64];
    }
    ((float4*)out)[i] = res;
}

extern "C" void kernel_launch(void* const* d_in, const int* in_sizes, int n_in,
                              void* d_out, int out_size, void* d_ws, size_t ws_size,
                              hipStream_t stream)
{
    const float* x     = (const float*)d_in[0];
    const int*   ei    = (const int*)d_in[1];
    // d_in[2] = edge_attr (unused)
    const float* u     = (const float*)d_in[3];
    const int*   batch = (const int*)d_in[4];
    const float* W1    = (const float*)d_in[5];
    const float* b1    = (const float*)d_in[6];
    const float* W2    = (const float*)d_in[7];
    const float* b2    = (const float*)d_in[8];
    const float* W3    = (const float*)d_in[9];
    const float* b3    = (const float*)d_in[10];
    float* out = (float*)d_out;

    // ws layout (16B-aligned segments)
    unsigned short* wp     = (unsigned short*)d_ws;                    //    81,920 B
    int*            cnt    = (int*)((char*)d_ws + 81920);              //   200,000 B
    int*            off    = (int*)((char*)d_ws + 281920);             //   200,000 B
    int2*           enodes = (int2*)((char*)d_ws + 481920);            // 6,400,000 B
    unsigned short* xbf    = (unsigned short*)((char*)d_ws + 6881920); // 6,400,000 B

    setup_kernel<<<(SETUP_TOTAL + 255) / 256, 256, 0, stream>>>(x, W1, W2, W3, wp, xbf, cnt, out);
    hist_kernel<<<(E_EDGES + 255) / 256, 256, 0, stream>>>(ei, cnt);
    scan_kernel<<<1, 1024, 0, stream>>>(cnt, off);
    scatter_kernel<<<(E_EDGES + 255) / 256, 256, 0, stream>>>(ei, off, enodes);
    edge_mlp_kernel<<<E_EDGES / 64, 256, 0, stream>>>(xbf, enodes, wp, b1, b2, b3, out);
    long finN = (long)NN * 72;
    finalize_kernel<<<(int)((finN + 255) / 256), 256, 0, stream>>>(x, u, batch, cnt, out);
}